// Round 3
// baseline (313.749 us; speedup 1.0000x reference)
//
#include <hip/hip_runtime.h>

// AttentionLoss: out = sum_{valid}(guide * pred) / sum(tl*ml)
// guide = 1 - exp(-12.5*(n/tl - t/ml)^2);  valid: t < ml[b] && n < tl[b]
// pred [B=64, MEL=2000, TEXT=256] f32; lengths int32 [64].
//
// R2 structure (one batch per block-group, one wave per row, float4 loads)
// + R3 fusion: single kernel, last-block-done pattern reduces partials.
// d_ws layout: [0..3] atomic ticket counter (memset to 0 on stream),
//              [64..] 2048 float partials.

#define BB 64
#define MEL_MAX 2000
#define TEXT_MAX 256
#define BLK_PER_B 32
#define NBLOCKS (BB * BLK_PER_B)   // 2048

__global__ __launch_bounds__(256) void attn_fused(
    const float* __restrict__ pred,
    const int* __restrict__ text_len,
    const int* __restrict__ mel_len,
    unsigned int* __restrict__ counter,   // d_ws + 0, pre-zeroed
    float* __restrict__ partials,         // d_ws + 64B
    float* __restrict__ out)
{
    const int b    = blockIdx.x >> 5;        // 0..63
    const int j    = blockIdx.x & 31;        // 0..31
    const int wave = threadIdx.x >> 6;       // 0..3
    const int lane = threadIdx.x & 63;       // 0..63

    const int mlb = mel_len[b];
    const int tlb = text_len[b];
    const float inv_tl = 1.0f / (float)tlb;
    const float inv_ml = 1.0f / (float)mlb;

    const int n0 = lane << 2;                 // first of 4 text positions
    const float nbase = (float)n0 * inv_tl;
    const bool lane_live = (n0 < tlb);

    const float* bbase = pred + (size_t)b * MEL_MAX * TEXT_MAX;

    float acc = 0.0f;
    for (int t = (j << 2) + wave; t < mlb; t += BLK_PER_B * 4) {
        float4 v;
        if (lane_live)
            v = *(const float4*)(bbase + (size_t)t * TEXT_MAX + n0);
        const float base_d = nbase - (float)t * inv_ml;
        #pragma unroll
        for (int e = 0; e < 4; e++) {
            const float d = base_d + (float)e * inv_tl;
            const float g = 1.0f - __expf(-12.5f * d * d);
            const float pv = (&v.x)[e];
            acc += (n0 + e < tlb) ? g * pv : 0.0f;
        }
    }

    // block reduction: wave64 shuffle then LDS across 4 waves
    for (int off = 32; off > 0; off >>= 1)
        acc += __shfl_down(acc, off, 64);
    __shared__ float s[4];
    __shared__ bool s_last;
    if (lane == 0) s[wave] = acc;
    __syncthreads();
    if (threadIdx.x == 0) {
        partials[blockIdx.x] = s[0] + s[1] + s[2] + s[3];
        __threadfence();                               // release partial
        unsigned int old = atomicAdd(counter, 1u);     // device scope
        s_last = (old == NBLOCKS - 1);
    }
    __syncthreads();

    if (s_last) {
        __threadfence();                               // acquire partials
        float a = 0.0f;
        for (int i = threadIdx.x; i < NBLOCKS; i += 256)
            a += partials[i];
        for (int off = 32; off > 0; off >>= 1)
            a += __shfl_down(a, off, 64);
        __shared__ float s2[4];
        if ((threadIdx.x & 63) == 0) s2[threadIdx.x >> 6] = a;
        __syncthreads();
        if (threadIdx.x < 64) {
            // parallel active = sum tl[b]*ml[b] over 64 batches (wave 0)
            float av = (float)text_len[threadIdx.x] * (float)mel_len[threadIdx.x];
            for (int off = 32; off > 0; off >>= 1)
                av += __shfl_down(av, off, 64);
            if (threadIdx.x == 0) {
                const float loss = s2[0] + s2[1] + s2[2] + s2[3];
                out[0] = loss / av;   // ATTN_WEIGHT = 1.0
            }
        }
    }
}

extern "C" void kernel_launch(void* const* d_in, const int* in_sizes, int n_in,
                              void* d_out, int out_size, void* d_ws, size_t ws_size,
                              hipStream_t stream)
{
    // inputs: 0 = targets (unused zeros), 1 = predictions, 2 = text_lengths, 3 = mel_lengths
    const float* pred = (const float*)d_in[1];
    const int* tl = (const int*)d_in[2];
    const int* ml = (const int*)d_in[3];
    float* out = (float*)d_out;
    unsigned int* counter = (unsigned int*)d_ws;
    float* partials = (float*)((char*)d_ws + 64);

    hipMemsetAsync(counter, 0, sizeof(unsigned int), stream);
    attn_fused<<<NBLOCKS, 256, 0, stream>>>(pred, tl, ml, counter, partials, out);
}

// Round 4
// 256.437 us; speedup vs baseline: 1.2235x; 1.2235x over previous
//
#include <hip/hip_runtime.h>

// AttentionLoss: out = sum_{valid}(guide * pred) / sum(tl*ml)
// guide = 1 - exp(-12.5*(n/tl - t/ml)^2);  valid: t < ml[b] && n < tl[b]
// pred [B=64, MEL=2000, TEXT=256] f32; lengths int32 [64].
//
// R4: two kernels (NO atomics, NO threadfence — R3 showed 2048 same-address
// atomics serialize at the coherence point, ~110 us). Work distribution is
// globally balanced: 8192 waves grid-stride over mel rows of every batch,
// so per-wave work ~= mean (~8 row-loads) regardless of length skew.

#define BB 64
#define MEL_MAX 2000
#define TEXT_MAX 256
#define NBLOCKS 2048
#define NWAVES (NBLOCKS * 4)   // 8192 global waves

__global__ __launch_bounds__(256) void attn_partial(
    const float* __restrict__ pred,
    const int* __restrict__ text_len,
    const int* __restrict__ mel_len,
    float* __restrict__ partials)
{
    const int wave = threadIdx.x >> 6;       // 0..3
    const int lane = threadIdx.x & 63;       // 0..63
    const int gw   = (blockIdx.x << 2) + wave;   // global wave id 0..8191

    const int n0 = lane << 2;                // first of 4 text positions

    float acc = 0.0f;
    for (int b = 0; b < BB; b++) {
        const int mlb = mel_len[b];          // scalar, L1-hot after block 0
        const int tlb = text_len[b];
        const float inv_tl = 1.0f / (float)tlb;
        const float inv_ml = 1.0f / (float)mlb;
        const float nbase = (float)n0 * inv_tl;
        const bool lane_live = (n0 < tlb);
        const float* bbase = pred + (size_t)b * MEL_MAX * TEXT_MAX;

        // balanced: each global wave takes rows gw, gw+8192, ... (< mlb)
        for (int t = gw; t < mlb; t += NWAVES) {
            float4 v;
            if (lane_live)
                v = *(const float4*)(bbase + (size_t)t * TEXT_MAX + n0);
            const float base_d = nbase - (float)t * inv_ml;
            #pragma unroll
            for (int e = 0; e < 4; e++) {
                const float d = base_d + (float)e * inv_tl;
                const float g = 1.0f - __expf(-12.5f * d * d);
                const float pv = (&v.x)[e];
                acc += (n0 + e < tlb) ? g * pv : 0.0f;
            }
        }
    }

    // block reduction: wave64 shuffle then LDS across 4 waves
    for (int off = 32; off > 0; off >>= 1)
        acc += __shfl_down(acc, off, 64);
    __shared__ float s[4];
    if (lane == 0) s[wave] = acc;
    __syncthreads();
    if (threadIdx.x == 0)
        partials[blockIdx.x] = s[0] + s[1] + s[2] + s[3];
}

__global__ __launch_bounds__(256) void attn_final(
    const float* __restrict__ partials,
    const int* __restrict__ text_len,
    const int* __restrict__ mel_len,
    float* __restrict__ out)
{
    float acc = 0.0f;
    for (int i = threadIdx.x; i < NBLOCKS; i += 256)
        acc += partials[i];
    for (int off = 32; off > 0; off >>= 1)
        acc += __shfl_down(acc, off, 64);
    __shared__ float s[4];
    const int wid = threadIdx.x >> 6;
    if ((threadIdx.x & 63) == 0) s[wid] = acc;
    __syncthreads();

    // active = sum tl[b]*ml[b], parallel over wave 0
    if (threadIdx.x < 64) {
        float av = (float)text_len[threadIdx.x] * (float)mel_len[threadIdx.x];
        for (int off = 32; off > 0; off >>= 1)
            av += __shfl_down(av, off, 64);
        if (threadIdx.x == 0) {
            const float loss = s[0] + s[1] + s[2] + s[3];
            out[0] = loss / av;   // ATTN_WEIGHT = 1.0
        }
    }
}

extern "C" void kernel_launch(void* const* d_in, const int* in_sizes, int n_in,
                              void* d_out, int out_size, void* d_ws, size_t ws_size,
                              hipStream_t stream)
{
    // inputs: 0 = targets (unused zeros), 1 = predictions, 2 = text_lengths, 3 = mel_lengths
    const float* pred = (const float*)d_in[1];
    const int* tl = (const int*)d_in[2];
    const int* ml = (const int*)d_in[3];
    float* out = (float*)d_out;
    float* partials = (float*)d_ws;   // NBLOCKS floats

    attn_partial<<<NBLOCKS, 256, 0, stream>>>(pred, tl, ml, partials);
    attn_final<<<1, 256, 0, stream>>>(partials, tl, ml, out);
}

// Round 5
// 235.663 us; speedup vs baseline: 1.3313x; 1.0882x over previous
//
#include <hip/hip_runtime.h>

// AttentionLoss: out = sum_{valid}(guide * pred) / sum(tl*ml)
// guide = 1 - exp(-12.5*(n/tl - t/ml)^2);  valid: t < ml[b] && n < tl[b]
// pred [B=64, MEL=2000, TEXT=256] f32; lengths int32 [64].
//
// R5: flat-row balancing. Global row index r in [0, B*MEL_MAX); wave gw
// handles rows r = gw + k*8192  (~15.6 rows/wave, perfectly balanced under
// any length skew — fixes R2's per-batch 2x imbalance and R4's stride bug
// where only waves gw<2000 had work). No atomics/fences (R3 lesson:
// 2048 same-address device atomics serialize ~110us).

#define BB 64
#define MEL_MAX 2000
#define TEXT_MAX 256
#define NBLOCKS 2048
#define NWAVES (NBLOCKS * 4)       // 8192 global waves
#define NROWS (BB * MEL_MAX)       // 128000

__global__ __launch_bounds__(256) void attn_partial(
    const float* __restrict__ pred,
    const int* __restrict__ text_len,
    const int* __restrict__ mel_len,
    float* __restrict__ partials)
{
    const int wave = threadIdx.x >> 6;           // 0..3
    const int lane = threadIdx.x & 63;           // 0..63
    const int gw   = (blockIdx.x << 2) + wave;   // global wave 0..8191
    const int n0   = lane << 2;                  // 4 text positions/lane

    float acc = 0.0f;
    for (int row = gw; row < NROWS; row += NWAVES) {
        const int b = row / MEL_MAX;             // magic-mul, wave-uniform
        const int t = row - b * MEL_MAX;
        const int mlb = mel_len[b];              // L1-hot scalar load
        if (t >= mlb) continue;                  // invalid row: no vector load
        const int tlb = text_len[b];
        const float inv_tl = 1.0f / (float)tlb;
        const float inv_ml = 1.0f / (float)mlb;

        float4 v;
        if (n0 < tlb)
            v = *(const float4*)(pred + (size_t)row * TEXT_MAX + n0);
        const float base_d = (float)n0 * inv_tl - (float)t * inv_ml;
        #pragma unroll
        for (int e = 0; e < 4; e++) {
            const float d = base_d + (float)e * inv_tl;
            const float g = 1.0f - __expf(-12.5f * d * d);
            const float pv = (&v.x)[e];
            acc += (n0 + e < tlb) ? g * pv : 0.0f;
        }
    }

    // block reduction: wave64 shuffle then LDS across 4 waves
    for (int off = 32; off > 0; off >>= 1)
        acc += __shfl_down(acc, off, 64);
    __shared__ float s[4];
    if (lane == 0) s[wave] = acc;
    __syncthreads();
    if (threadIdx.x == 0)
        partials[blockIdx.x] = s[0] + s[1] + s[2] + s[3];
}

__global__ __launch_bounds__(256) void attn_final(
    const float* __restrict__ partials,
    const int* __restrict__ text_len,
    const int* __restrict__ mel_len,
    float* __restrict__ out)
{
    float acc = 0.0f;
    for (int i = threadIdx.x; i < NBLOCKS; i += 256)
        acc += partials[i];
    for (int off = 32; off > 0; off >>= 1)
        acc += __shfl_down(acc, off, 64);
    __shared__ float s[4];
    const int wid = threadIdx.x >> 6;
    if ((threadIdx.x & 63) == 0) s[wid] = acc;
    __syncthreads();

    // active = sum tl[b]*ml[b], parallel over wave 0
    if (threadIdx.x < 64) {
        float av = (float)text_len[threadIdx.x] * (float)mel_len[threadIdx.x];
        for (int off = 32; off > 0; off >>= 1)
            av += __shfl_down(av, off, 64);
        if (threadIdx.x == 0) {
            const float loss = s[0] + s[1] + s[2] + s[3];
            out[0] = loss / av;   // ATTN_WEIGHT = 1.0
        }
    }
}

extern "C" void kernel_launch(void* const* d_in, const int* in_sizes, int n_in,
                              void* d_out, int out_size, void* d_ws, size_t ws_size,
                              hipStream_t stream)
{
    // inputs: 0 = targets (unused zeros), 1 = predictions, 2 = text_lengths, 3 = mel_lengths
    const float* pred = (const float*)d_in[1];
    const int* tl = (const int*)d_in[2];
    const int* ml = (const int*)d_in[3];
    float* out = (float*)d_out;
    float* partials = (float*)d_ws;   // NBLOCKS floats

    attn_partial<<<NBLOCKS, 256, 0, stream>>>(pred, tl, ml, partials);
    attn_final<<<1, 256, 0, stream>>>(partials, tl, ml, out);
}